// Round 6
// baseline (310.979 us; speedup 1.0000x reference)
//
#include <hip/hip_runtime.h>
#include <hip/hip_bf16.h>
#include <cstdint>
#include <cstddef>

typedef __bf16 bf16;
typedef __bf16 bf16x4 __attribute__((ext_vector_type(4)));
typedef __bf16 bf16x8 __attribute__((ext_vector_type(8)));
typedef float f32x4 __attribute__((ext_vector_type(4)));

#define D_MODEL 2048
#define SEQ     2048
#define NH      16
#define HD      128
#define BATCH   2
#define QKV_LD  6144

#define SBAR()  __builtin_amdgcn_sched_barrier(0)
#define HWBAR() do { SBAR(); __builtin_amdgcn_s_barrier(); SBAR(); } while (0)

// ---------------- async global->LDS 16B ----------------
__device__ __forceinline__ void gld16(void* lds, const void* g) {
    __builtin_amdgcn_global_load_lds(
        (const __attribute__((address_space(1))) unsigned int*)g,
        (__attribute__((address_space(3))) unsigned int*)lds,
        16, 0, 0);
}

// ---------------- fused fp32 -> bf16 convert (x, Wq, Wk, Wv, Wo) ----------------
// dest segments are contiguous in ws: xb(8M) | wqkv(12M) | wob(4M) elems.
__global__ __launch_bounds__(256) void cvt_all(const float* __restrict__ x,
                                               const float* __restrict__ Wq,
                                               const float* __restrict__ Wk,
                                               const float* __restrict__ Wv,
                                               const float* __restrict__ Wo,
                                               bf16* __restrict__ out) {
    int i = (blockIdx.x * 256 + threadIdx.x) * 4;  // 25165824 total elems
    const float* src;
    int off;
    if (i < 8388608) { src = x; off = i; }
    else {
        int j = i - 8388608;
        int seg = j >> 22;
        src = (seg == 0) ? Wq : (seg == 1) ? Wk : (seg == 2) ? Wv : Wo;
        off = j & 4194303;
    }
    float4 v = *(const float4*)(src + off);
    bf16* o = out + i;
    o[0] = (bf16)v.x; o[1] = (bf16)v.y; o[2] = (bf16)v.z; o[3] = (bf16)v.w;
}

// ---------------- RoPE tables (cos/sin, S x 64) ----------------
__global__ __launch_bounds__(256) void rope_tables_k(float* __restrict__ cosd,
                                                     float* __restrict__ sind) {
    int id = blockIdx.x * 256 + threadIdx.x;  // SEQ*64
    int s = id >> 6, d = id & 63;
    float freq = powf(10000.f, -(float)d * (1.f / 64.f));
    float a = (float)s * freq;
    float sn, c;
    sincosf(a, &sn, &c);
    cosd[id] = c;
    sind[id] = sn;
}

// ---------------- RoPE apply (in-place, row stride ld) ----------------
__global__ __launch_bounds__(256) void rope_apply(bf16* __restrict__ T,
                                                  const float* __restrict__ cosd,
                                                  const float* __restrict__ sind,
                                                  float scale, int ld) {
    int id = blockIdx.x * 256 + threadIdx.x;   // B*S*NH*64
    int row = id >> 10;                        // B*S
    int p = id & 1023;
    int h = p >> 6, d = p & 63;
    int s = row & (SEQ - 1);
    size_t base = (size_t)row * ld + h * HD + d;
    float x1 = (float)T[base];
    float x2 = (float)T[base + 64];
    float c = cosd[(s << 6) + d];
    float sn = sind[(s << 6) + d];
    T[base]      = (bf16)((x1 * c - x2 * sn) * scale);
    T[base + 64] = (bf16)((x2 * c + x1 * sn) * scale);
}

// ---------------- V transpose: [B,S,(ld)] head cols -> [B,H,D,S] ----------------
__global__ __launch_bounds__(256) void transpose_v(const bf16* __restrict__ V,
                                                   bf16* __restrict__ Vt, int ld) {
    __shared__ bf16 t[32][33];
    int s0 = blockIdx.x * 32;
    int d0 = blockIdx.y * 32;
    int bh = blockIdx.z;
    int b = bh >> 4, h = bh & 15;
    int tx = threadIdx.x & 31, ty = threadIdx.x >> 5;  // ty 0..7
#pragma unroll
    for (int i = 0; i < 32; i += 8)
        t[ty + i][tx] = V[((size_t)(b * SEQ + s0 + ty + i)) * ld + h * HD + d0 + tx];
    __syncthreads();
#pragma unroll
    for (int i = 0; i < 32; i += 8)
        Vt[((size_t)bh * HD + d0 + ty + i) * SEQ + s0 + tx] = t[tx][ty + i];
}

// ---------------- 256x256 NT GEMM, deep-pipelined 4-phase ----------------
// C[M,N] = A[M,K] * B[N,K]^T. 512 thr = 8 waves (2m x 4n), BK=64,
// double-buffered 128 KiB LDS, row-XOR swizzle, region-derived stage schedule:
//   phase0: stage (t+1).B0   phase1: stage (t+1).B1
//   phase3: stage (t+2).A0 + (t+2).A1   (A regions free after phase2 barrier)
// boundary wait vmcnt(4) keeps the two t+2 A-units in flight.
template <int OUTF32>
__global__ __launch_bounds__(512, 2)
void gemm8p(const bf16* __restrict__ A, const bf16* __restrict__ B,
            void* __restrict__ Cout, int M, int N, int K) {
    __shared__ __align__(16) bf16 ldsAB[2][2][2][128 * 64];  // [buf][A/B][unit][128x64]

    const int nM = M >> 8, nN = N >> 8;
    const int cpx = (nM * nN) >> 3;

    // 2D XCD chunk shape: chm*chn = cpx, nM%chm==0, nN%chn==0, min perimeter
    int bchm = 0, bchn = 0, best = 0x7fffffff;
    for (int d = 1; d <= cpx; ++d) {
        if (cpx % d) continue;
        int cm = cpx / d;
        if (nM % cm || nN % d) continue;
        if (cm + d < best) { best = cm + d; bchm = cm; bchn = d; }
    }
    int mt0, nt0;
    if (bchm) {
        const int ncn = nN / bchn;                 // chunk cols
        const int xcd = blockIdx.x & 7, loc = blockIdx.x >> 3;
        mt0 = (xcd / ncn) * bchm + loc / bchn;
        nt0 = (xcd % ncn) * bchn + loc % bchn;
    } else {                                       // fallback: linear
        const int lin = (blockIdx.x & 7) * cpx + (blockIdx.x >> 3);
        mt0 = lin / nN; nt0 = lin % nN;
    }
    const int m0 = mt0 * 256, n0 = nt0 * 256;

    const int tid = threadIdx.x;
    const int w = tid >> 6, l = tid & 63;
    const int wm = w >> 2, wn = w & 3;
    const int lg = l >> 4, lc = l & 15;
    const int swz = (lc & 7) << 4;
    const int NT = K >> 6;

    f32x4 acc[2][2][4][2] = {};

    // stage unit u of K-tile tau: u 0=A rows0-127, 1=A rows128-255, 2=B0, 3=B1
    auto stageU = [&](int tau, int u) {
        bf16* dst = &ldsAB[tau & 1][u >> 1][u & 1][0];
        const bf16* src = (u < 2) ? A + (size_t)(m0 + (u & 1) * 128) * K
                                  : B + (size_t)(n0 + (u & 1) * 128) * K;
#pragma unroll
        for (int j = 0; j < 2; ++j) {
            int r = w * 8 + j * 64 + (l >> 3);
            int scb = ((l & 7) * 16) ^ ((r & 7) << 4);
            gld16(dst + (w * 8 + j * 64) * 64, src + (size_t)r * K + tau * 64 + (scb >> 1));
        }
    };

    // prologue: tile0 all units + tile1 A units; wait tile0 (4 loads in flight)
    stageU(0, 0); stageU(0, 1); stageU(0, 2); stageU(0, 3);
    stageU(1, 0); stageU(1, 1);
    SBAR();
    asm volatile("s_waitcnt vmcnt(4)" ::: "memory");
    HWBAR();

    for (int t = 0; t < NT; ++t) {
        const int c = t & 1;
        const char* Ab = (const char*)&ldsAB[c][0][wm][0];
        const char* Bb = (const char*)&ldsAB[c][1][wn >> 1][0];
        const int brow0 = (wn & 1) * 64;
        bf16x8 Af[4][2], Bf[2][2][2];

        // ---- phase 0: (mq0, nq0); stage (t+1).B0 ----
#pragma unroll
        for (int mt = 0; mt < 4; ++mt)
#pragma unroll
            for (int ks = 0; ks < 2; ++ks)
                Af[mt][ks] = *(const bf16x8*)(Ab + (mt * 16 + lc) * 128 + ((ks * 64 + lg * 16) ^ swz));
#pragma unroll
        for (int nt = 0; nt < 2; ++nt)
#pragma unroll
            for (int ks = 0; ks < 2; ++ks)
                Bf[0][nt][ks] = *(const bf16x8*)(Bb + (brow0 + nt * 16 + lc) * 128 + ((ks * 64 + lg * 16) ^ swz));
        if (t + 1 < NT) stageU(t + 1, 2);
        HWBAR();
        __builtin_amdgcn_s_setprio(1);
#pragma unroll
        for (int mt = 0; mt < 4; ++mt)
#pragma unroll
            for (int nt = 0; nt < 2; ++nt)
#pragma unroll
                for (int ks = 0; ks < 2; ++ks)
                    acc[0][0][mt][nt] = __builtin_amdgcn_mfma_f32_16x16x32_bf16(Af[mt][ks], Bf[0][nt][ks], acc[0][0][mt][nt], 0, 0, 0);
        __builtin_amdgcn_s_setprio(0);
        HWBAR();

        // ---- phase 1: (mq0, nq1); stage (t+1).B1 ----
#pragma unroll
        for (int nt = 0; nt < 2; ++nt)
#pragma unroll
            for (int ks = 0; ks < 2; ++ks)
                Bf[1][nt][ks] = *(const bf16x8*)(Bb + (brow0 + 32 + nt * 16 + lc) * 128 + ((ks * 64 + lg * 16) ^ swz));
        if (t + 1 < NT) stageU(t + 1, 3);
        HWBAR();
        __builtin_amdgcn_s_setprio(1);
#pragma unroll
        for (int mt = 0; mt < 4; ++mt)
#pragma unroll
            for (int nt = 0; nt < 2; ++nt)
#pragma unroll
                for (int ks = 0; ks < 2; ++ks)
                    acc[0][1][mt][nt] = __builtin_amdgcn_mfma_f32_16x16x32_bf16(Af[mt][ks], Bf[1][nt][ks], acc[0][1][mt][nt], 0, 0, 0);
        __builtin_amdgcn_s_setprio(0);
        HWBAR();

        // ---- phase 2: (mq1, nq0); re-read A(mq1); no stage ----
#pragma unroll
        for (int mt = 0; mt < 4; ++mt)
#pragma unroll
            for (int ks = 0; ks < 2; ++ks)
                Af[mt][ks] = *(const bf16x8*)(Ab + (64 + mt * 16 + lc) * 128 + ((ks * 64 + lg * 16) ^ swz));
        HWBAR();
        __builtin_amdgcn_s_setprio(1);
#pragma unroll
        for (int mt = 0; mt < 4; ++mt)
#pragma unroll
            for (int nt = 0; nt < 2; ++nt)
#pragma unroll
                for (int ks = 0; ks < 2; ++ks)
                    acc[1][0][mt][nt] = __builtin_amdgcn_mfma_f32_16x16x32_bf16(Af[mt][ks], Bf[0][nt][ks], acc[1][0][mt][nt], 0, 0, 0);
        __builtin_amdgcn_s_setprio(0);
        HWBAR();

        // ---- phase 3: (mq1, nq1); stage (t+2).A0+A1 (regions free after ph2) ----
        if (t + 2 < NT) { stageU(t + 2, 0); stageU(t + 2, 1); }
        __builtin_amdgcn_s_setprio(1);
#pragma unroll
        for (int mt = 0; mt < 4; ++mt)
#pragma unroll
            for (int nt = 0; nt < 2; ++nt)
#pragma unroll
                for (int ks = 0; ks < 2; ++ks)
                    acc[1][1][mt][nt] = __builtin_amdgcn_mfma_f32_16x16x32_bf16(Af[mt][ks], Bf[1][nt][ks], acc[1][1][mt][nt], 0, 0, 0);
        __builtin_amdgcn_s_setprio(0);
        SBAR();
        if (t + 2 < NT) asm volatile("s_waitcnt vmcnt(4)" ::: "memory");
        else            asm volatile("s_waitcnt vmcnt(0)" ::: "memory");
        HWBAR();
    }

    // ---- epilogue ----
#pragma unroll
    for (int mq = 0; mq < 2; ++mq)
#pragma unroll
        for (int nq = 0; nq < 2; ++nq)
#pragma unroll
            for (int mt = 0; mt < 4; ++mt)
#pragma unroll
                for (int nt = 0; nt < 2; ++nt)
#pragma unroll
                    for (int rr = 0; rr < 4; ++rr) {
                        size_t row = (size_t)m0 + wm * 128 + mq * 64 + mt * 16 + lg * 4 + rr;
                        size_t col = (size_t)n0 + wn * 64 + nq * 32 + nt * 16 + lc;
                        float v = acc[mq][nq][mt][nt][rr];
                        if (OUTF32) ((float*)Cout)[row * N + col] = v;
                        else        ((bf16*)Cout)[row * N + col] = (bf16)v;
                    }
}

// ---------------- Flash attention (unchanged from R5) ----------------
__global__ __launch_bounds__(256)
void flash_attn(const bf16* __restrict__ QKV, const bf16* __restrict__ Vt,
                bf16* __restrict__ O) {
    __shared__ __align__(16) bf16 Ks[2][64 * 128];   // [key][d], rows 256B
    __shared__ __align__(16) bf16 Vs[2][128 * 64];   // [d][key], rows 128B
    __shared__ __align__(16) bf16 p_lds[4][16 * 64]; // per-wave P[q][key], rows 128B

    const int bid = blockIdx.x;                   // 512
    const int lin = (bid & 7) * 64 + (bid >> 3);  // XCD-chunked
    const int bh = lin >> 4;
    const int jj = lin & 15;
    const int b = bh >> 4, h = bh & 15;

    const int tid = threadIdx.x;
    const int w = tid >> 6, l = tid & 63;
    const int lg = l >> 4, lc = l & 15;
    const int kswz = (lc & 7) << 4;
    char* pb = (char*)&p_lds[w][0];

    auto stageK = [&](int p, int kb) {
#pragma unroll
        for (int c = 0; c < 4; ++c) {
            int r = c * 16 + w * 4 + (l >> 4);
            int scb = ((l & 15) * 16) ^ ((r & 7) << 4);
            const bf16* g = QKV + ((size_t)(b * SEQ + kb * 64 + r)) * QKV_LD + D_MODEL + h * HD + (scb >> 1);
            gld16(&Ks[p][(c * 16 + w * 4) * 128], g);
        }
    };
    auto stageV = [&](int p, int kb) {
#pragma unroll
        for (int c = 0; c < 4; ++c) {
            int r = c * 32 + w * 8 + (l >> 3);
            int scb = ((l & 7) * 16) ^ ((r & 7) << 4);
            const bf16* g = Vt + ((size_t)bh * HD + r) * SEQ + kb * 64 + (scb >> 1);
            gld16(&Vs[p][(c * 32 + w * 8) * 64], g);
        }
    };

    int cur = 0;
#pragma unroll 1
    for (int ti = 0; ti < 2; ++ti) {
        const int qt = ti ? jj : (31 - jj);       // long tile first
        const int q0 = qt * 64 + w * 16;

        const bf16* qp = QKV + ((size_t)(b * SEQ + q0 + lc)) * QKV_LD + h * HD + lg * 8;
        bf16x8 qf[4];
#pragma unroll
        for (int kc = 0; kc < 4; ++kc) qf[kc] = *(const bf16x8*)(qp + kc * 32);

        f32x4 ctx[8] = {};
        float m_s = -INFINITY, l_s = 0.f;

        stageK(cur, 0);
        stageV(cur, 0);

        for (int kb = 0; kb <= qt; ++kb) {
            __syncthreads();
            if (kb < qt) { stageK(cur ^ 1, kb + 1); stageV(cur ^ 1, kb + 1); }

            const char* kbp = (const char*)&Ks[cur][0];
            f32x4 st[4] = {};
#pragma unroll
            for (int nf = 0; nf < 4; ++nf) {
                int krow = nf * 16 + lc;
#pragma unroll
                for (int kc = 0; kc < 4; ++kc) {
                    bf16x8 kf = *(const bf16x8*)(kbp + krow * 256 + ((kc * 64 + lg * 16) ^ kswz));
                    st[nf] = __builtin_amdgcn_mfma_f32_16x16x32_bf16(kf, qf[kc], st[nf], 0, 0, 0);
                }
            }

            if (kb == qt) {
                int q = q0 + lc;
#pragma unroll
                for (int nf = 0; nf < 4; ++nf) {
                    int key = kb * 64 + nf * 16 + lg * 4;
#pragma unroll
                    for (int r = 0; r < 4; ++r)
                        if (key + r > q) st[nf][r] = -INFINITY;
                }
            }

            float mx = -INFINITY;
#pragma unroll
            for (int nf = 0; nf < 4; ++nf)
#pragma unroll
                for (int r = 0; r < 4; ++r) mx = fmaxf(mx, st[nf][r]);
            mx = fmaxf(mx, __shfl_xor(mx, 16));
            mx = fmaxf(mx, __shfl_xor(mx, 32));
            float mi = fmaxf(m_s, mx);
            float scv = __expf(m_s - mi);
            m_s = mi;

            float rs = 0.f;
#pragma unroll
            for (int nf = 0; nf < 4; ++nf) {
                float p0 = __expf(st[nf][0] - mi);
                float p1 = __expf(st[nf][1] - mi);
                float p2 = __expf(st[nf][2] - mi);
                float p3 = __expf(st[nf][3] - mi);
                rs += (p0 + p1) + (p2 + p3);
                bf16x4 pv = { (bf16)p0, (bf16)p1, (bf16)p2, (bf16)p3 };
                *(bf16x4*)(pb + lc * 128 + ((nf * 32 + lg * 8) ^ kswz)) = pv;
            }
            rs += __shfl_xor(rs, 16);
            rs += __shfl_xor(rs, 32);
            l_s = l_s * scv + rs;

            float scvr[4];
#pragma unroll
            for (int r = 0; r < 4; ++r) scvr[r] = __shfl(scv, lg * 4 + r);
#pragma unroll
            for (int nd = 0; nd < 8; ++nd)
#pragma unroll
                for (int r = 0; r < 4; ++r) ctx[nd][r] *= scvr[r];

            asm volatile("s_waitcnt lgkmcnt(0)" ::: "memory");
            SBAR();
            bf16x8 pa0 = *(const bf16x8*)(pb + lc * 128 + ((lg * 16) ^ kswz));
            bf16x8 pa1 = *(const bf16x8*)(pb + lc * 128 + ((64 + lg * 16) ^ kswz));

            const char* vb = (const char*)&Vs[cur][0];
#pragma unroll
            for (int nd = 0; nd < 8; ++nd) {
                int vrow = nd * 16 + lc;
#pragma unroll
                for (int k2 = 0; k2 < 2; ++k2) {
                    bf16x8 vf = *(const bf16x8*)(vb + vrow * 128 + ((k2 * 64 + lg * 16) ^ kswz));
                    ctx[nd] = __builtin_amdgcn_mfma_f32_16x16x32_bf16(k2 ? pa1 : pa0, vf, ctx[nd], 0, 0, 0);
                }
            }
            cur ^= 1;
        }

        float lr[4];
#pragma unroll
        for (int r = 0; r < 4; ++r) lr[r] = 1.f / __shfl(l_s, lg * 4 + r);
#pragma unroll
        for (int nd = 0; nd < 8; ++nd)
#pragma unroll
            for (int r = 0; r < 4; ++r)
                O[((size_t)(b * SEQ + q0 + lg * 4 + r)) * D_MODEL + h * HD + nd * 16 + lc] =
                    (bf16)(ctx[nd][r] * lr[r]);
    }
}

// ---------------- launch ----------------
extern "C" void kernel_launch(void* const* d_in, const int* in_sizes, int n_in,
                              void* d_out, int out_size, void* d_ws, size_t ws_size,
                              hipStream_t stream) {
    const float* x  = (const float*)d_in[0];
    const float* Wq = (const float*)d_in[1];
    const float* Wk = (const float*)d_in[2];
    const float* Wv = (const float*)d_in[3];
    const float* Wo = (const float*)d_in[4];

    char* ws = (char*)d_ws;
    bf16* xb   = (bf16*)(ws + 0);            // 16 MB; reused as ctx after QKV GEMM
    bf16* wqkv = (bf16*)(ws + 16777216);     // 24 MB  [6144][2048]
    bf16* wob  = (bf16*)(ws + 41943040);     // 8 MB
    bf16* QKV  = (bf16*)(ws + 50331648);     // 48 MB  [4096][6144]
    bf16* Vtb  = (bf16*)(ws + 100663296);    // 16 MB  [B,H,D,S]
    float* cosd = (float*)(ws + 117440512);
    float* sind = (float*)(ws + 117964800);

    // fused convert: 25165824 elems -> contiguous xb|wqkv|wob
    cvt_all<<<25165824 / 1024, 256, 0, stream>>>(x, Wq, Wk, Wv, Wo, xb);

    rope_tables_k<<<(SEQ * 64) / 256, 256, 0, stream>>>(cosd, sind);

    // fused QKV projection: [4096,2048] x [6144,2048]^T -> [4096,6144]
    gemm8p<0><<<dim3((QKV_LD / 256) * ((BATCH * SEQ) / 256)), 512, 0, stream>>>(
        xb, wqkv, QKV, BATCH * SEQ, QKV_LD, D_MODEL);

    const float qscale = 0.08838834764831845f;  // 1/sqrt(128)
    rope_apply<<<(BATCH * SEQ * 1024) / 256, 256, 0, stream>>>(QKV,           cosd, sind, qscale, QKV_LD);
    rope_apply<<<(BATCH * SEQ * 1024) / 256, 256, 0, stream>>>(QKV + D_MODEL, cosd, sind, 1.0f,   QKV_LD);

    transpose_v<<<dim3(SEQ / 32, HD / 32, BATCH * NH), 256, 0, stream>>>(QKV + 2 * D_MODEL, Vtb, QKV_LD);

    flash_attn<<<dim3(512), 256, 0, stream>>>(QKV, Vtb, xb /*ctx*/);

    // output projection: [4096,2048] x [2048,2048]^T -> d_out (f32)
    gemm8p<1><<<dim3((D_MODEL / 256) * ((BATCH * SEQ) / 256)), 512, 0, stream>>>(
        xb, wob, d_out, BATCH * SEQ, D_MODEL, D_MODEL);
}

// Round 7
// 293.692 us; speedup vs baseline: 1.0589x; 1.0589x over previous
//
#include <hip/hip_runtime.h>
#include <hip/hip_bf16.h>
#include <cstdint>
#include <cstddef>

typedef __bf16 bf16;
typedef __bf16 bf16x4 __attribute__((ext_vector_type(4)));
typedef __bf16 bf16x8 __attribute__((ext_vector_type(8)));
typedef float f32x4 __attribute__((ext_vector_type(4)));

#define D_MODEL 2048
#define SEQ     2048
#define NH      16
#define HD      128
#define BATCH   2
#define QKV_LD  6144

#define SBAR()  __builtin_amdgcn_sched_barrier(0)
#define HWBAR() do { SBAR(); __builtin_amdgcn_s_barrier(); SBAR(); } while (0)

// ---------------- async global->LDS 16B ----------------
__device__ __forceinline__ void gld16(void* lds, const void* g) {
    __builtin_amdgcn_global_load_lds(
        (const __attribute__((address_space(1))) unsigned int*)g,
        (__attribute__((address_space(3))) unsigned int*)lds,
        16, 0, 0);
}

// ---------------- fused fp32 -> bf16 convert (x, Wq, Wk, Wv, Wo) ----------------
__global__ __launch_bounds__(256) void cvt_all(const float* __restrict__ x,
                                               const float* __restrict__ Wq,
                                               const float* __restrict__ Wk,
                                               const float* __restrict__ Wv,
                                               const float* __restrict__ Wo,
                                               bf16* __restrict__ out) {
    int i = (blockIdx.x * 256 + threadIdx.x) * 4;  // 25165824 total elems
    const float* src;
    int off;
    if (i < 8388608) { src = x; off = i; }
    else {
        int j = i - 8388608;
        int seg = j >> 22;
        src = (seg == 0) ? Wq : (seg == 1) ? Wk : (seg == 2) ? Wv : Wo;
        off = j & 4194303;
    }
    float4 v = *(const float4*)(src + off);
    bf16* o = out + i;
    o[0] = (bf16)v.x; o[1] = (bf16)v.y; o[2] = (bf16)v.z; o[3] = (bf16)v.w;
}

// ---------------- RoPE tables (cos/sin, S x 64) ----------------
__global__ __launch_bounds__(256) void rope_tables_k(float* __restrict__ cosd,
                                                     float* __restrict__ sind) {
    int id = blockIdx.x * 256 + threadIdx.x;  // SEQ*64
    int s = id >> 6, d = id & 63;
    float freq = powf(10000.f, -(float)d * (1.f / 64.f));
    float a = (float)s * freq;
    float sn, c;
    sincosf(a, &sn, &c);
    cosd[id] = c;
    sind[id] = sn;
}

// ---------------- RoPE apply (in-place, row stride ld) ----------------
__global__ __launch_bounds__(256) void rope_apply(bf16* __restrict__ T,
                                                  const float* __restrict__ cosd,
                                                  const float* __restrict__ sind,
                                                  float scale, int ld) {
    int id = blockIdx.x * 256 + threadIdx.x;   // B*S*NH*64
    int row = id >> 10;                        // B*S
    int p = id & 1023;
    int h = p >> 6, d = p & 63;
    int s = row & (SEQ - 1);
    size_t base = (size_t)row * ld + h * HD + d;
    float x1 = (float)T[base];
    float x2 = (float)T[base + 64];
    float c = cosd[(s << 6) + d];
    float sn = sind[(s << 6) + d];
    T[base]      = (bf16)((x1 * c - x2 * sn) * scale);
    T[base + 64] = (bf16)((x2 * c + x1 * sn) * scale);
}

// ---------------- 256x256 NT GEMM (R5 schedule + 2D XCD chunks + V-split) ----
// OUTMODE: 0 = bf16 out, 1 = f32 out, 2 = bf16 out with cols>=4096 routed to
// Vt[B,H,D,S] (transpose fused into epilogue; V region NOT written to Cout).
template <int OUTMODE>
__global__ __launch_bounds__(512, 2)
void gemm8p(const bf16* __restrict__ A, const bf16* __restrict__ B,
            void* __restrict__ Cout, bf16* __restrict__ Vt,
            int M, int N, int K, int chm, int chn, int ncn) {
    __shared__ __align__(16) bf16 ldsAB[2][2][2][128 * 64];  // [buf][A/B][unit][128x64]

    const int xcd = blockIdx.x & 7, loc = blockIdx.x >> 3;
    const int mt0 = (xcd / ncn) * chm + loc / chn;
    const int nt0 = (xcd % ncn) * chn + loc % chn;
    const int m0 = mt0 * 256, n0 = nt0 * 256;

    const int tid = threadIdx.x;
    const int w = tid >> 6, l = tid & 63;
    const int wm = w >> 2, wn = w & 3;
    const int lg = l >> 4, lc = l & 15;
    const int swz = (lc & 7) << 4;
    const int NT = K >> 6;
    const int HMAX = NT * 4;

    f32x4 acc[2][2][4][2] = {};

    // stage unit H: tau=H>>2 K-tile, h=H&3: 0=A rows0-127,1=A rows128-255,2=B0,3=B1
    auto stage = [&](int H) {
        const int tau = H >> 2, h = H & 3;
        bf16* dst = &ldsAB[tau & 1][h >> 1][h & 1][0];
#pragma unroll
        for (int j = 0; j < 2; ++j) {
            int r = w * 8 + j * 64 + (l >> 3);
            int scb = ((l & 7) * 16) ^ ((r & 7) << 4);
            const bf16* g = (h < 2)
                ? A + (size_t)(m0 + (h & 1) * 128 + r) * K + tau * 64 + (scb >> 1)
                : B + (size_t)(n0 + (h & 1) * 128 + r) * K + tau * 64 + (scb >> 1);
            gld16(dst + (w * 8 + j * 64) * 64, g);
        }
    };

    stage(0); stage(1); stage(2); stage(3); stage(4);
    SBAR();
    asm volatile("s_waitcnt vmcnt(2)" ::: "memory");
    HWBAR();

    for (int t = 0; t < NT; ++t) {
        const int c = t & 1;
        const char* Ab = (const char*)&ldsAB[c][0][wm][0];
        const char* Bb = (const char*)&ldsAB[c][1][wn >> 1][0];
        const int brow0 = (wn & 1) * 64;
        bf16x8 Af[4][2], Bf[2][2][2];

        // ---- phase 0: (mq0, nq0); stage A1(t+1) ----
#pragma unroll
        for (int mt = 0; mt < 4; ++mt)
#pragma unroll
            for (int ks = 0; ks < 2; ++ks)
                Af[mt][ks] = *(const bf16x8*)(Ab + (mt * 16 + lc) * 128 + ((ks * 64 + lg * 16) ^ swz));
#pragma unroll
        for (int nt = 0; nt < 2; ++nt)
#pragma unroll
            for (int ks = 0; ks < 2; ++ks)
                Bf[0][nt][ks] = *(const bf16x8*)(Bb + (brow0 + nt * 16 + lc) * 128 + ((ks * 64 + lg * 16) ^ swz));
        { int H = 4 * t + 5; if (H < HMAX) stage(H); }
        HWBAR();
        __builtin_amdgcn_s_setprio(1);
#pragma unroll
        for (int mt = 0; mt < 4; ++mt)
#pragma unroll
            for (int nt = 0; nt < 2; ++nt)
#pragma unroll
                for (int ks = 0; ks < 2; ++ks)
                    acc[0][0][mt][nt] = __builtin_amdgcn_mfma_f32_16x16x32_bf16(Af[mt][ks], Bf[0][nt][ks], acc[0][0][mt][nt], 0, 0, 0);
        __builtin_amdgcn_s_setprio(0);
        HWBAR();

        // ---- phase 1: (mq0, nq1); stage B0(t+1) ----
#pragma unroll
        for (int nt = 0; nt < 2; ++nt)
#pragma unroll
            for (int ks = 0; ks < 2; ++ks)
                Bf[1][nt][ks] = *(const bf16x8*)(Bb + (brow0 + 32 + nt * 16 + lc) * 128 + ((ks * 64 + lg * 16) ^ swz));
        { int H = 4 * t + 6; if (H < HMAX) stage(H); }
        HWBAR();
        __builtin_amdgcn_s_setprio(1);
#pragma unroll
        for (int mt = 0; mt < 4; ++mt)
#pragma unroll
            for (int nt = 0; nt < 2; ++nt)
#pragma unroll
                for (int ks = 0; ks < 2; ++ks)
                    acc[0][1][mt][nt] = __builtin_amdgcn_mfma_f32_16x16x32_bf16(Af[mt][ks], Bf[1][nt][ks], acc[0][1][mt][nt], 0, 0, 0);
        __builtin_amdgcn_s_setprio(0);
        HWBAR();

        // ---- phase 2: (mq1, nq0); re-read A(mq1); stage B1(t+1) ----
#pragma unroll
        for (int mt = 0; mt < 4; ++mt)
#pragma unroll
            for (int ks = 0; ks < 2; ++ks)
                Af[mt][ks] = *(const bf16x8*)(Ab + (64 + mt * 16 + lc) * 128 + ((ks * 64 + lg * 16) ^ swz));
        { int H = 4 * t + 7; if (H < HMAX) stage(H); }
        HWBAR();
        __builtin_amdgcn_s_setprio(1);
#pragma unroll
        for (int mt = 0; mt < 4; ++mt)
#pragma unroll
            for (int nt = 0; nt < 2; ++nt)
#pragma unroll
                for (int ks = 0; ks < 2; ++ks)
                    acc[1][0][mt][nt] = __builtin_amdgcn_mfma_f32_16x16x32_bf16(Af[mt][ks], Bf[0][nt][ks], acc[1][0][mt][nt], 0, 0, 0);
        __builtin_amdgcn_s_setprio(0);
        HWBAR();

        // ---- phase 3: (mq1, nq1); stage A0(t+2) ----
        { int H = 4 * t + 8; if (H < HMAX) stage(H); }
        HWBAR();
        __builtin_amdgcn_s_setprio(1);
#pragma unroll
        for (int mt = 0; mt < 4; ++mt)
#pragma unroll
            for (int nt = 0; nt < 2; ++nt)
#pragma unroll
                for (int ks = 0; ks < 2; ++ks)
                    acc[1][1][mt][nt] = __builtin_amdgcn_mfma_f32_16x16x32_bf16(Af[mt][ks], Bf[1][nt][ks], acc[1][1][mt][nt], 0, 0, 0);
        __builtin_amdgcn_s_setprio(0);
        SBAR();
        // A0(t+2) staged only when t+2<NT: then 2 loads may stay in flight.
        if (t + 2 < NT) asm volatile("s_waitcnt vmcnt(2)" ::: "memory");
        else            asm volatile("s_waitcnt vmcnt(0)" ::: "memory");
        HWBAR();
    }

    // ---- epilogue ----
    const bool vregion = (OUTMODE == 2) && (n0 >= 2 * D_MODEL);
#pragma unroll
    for (int mq = 0; mq < 2; ++mq)
#pragma unroll
        for (int nq = 0; nq < 2; ++nq)
#pragma unroll
            for (int mt = 0; mt < 4; ++mt)
#pragma unroll
                for (int nt = 0; nt < 2; ++nt) {
                    size_t row0 = (size_t)m0 + wm * 128 + mq * 64 + mt * 16 + lg * 4;
                    size_t col  = (size_t)n0 + wn * 64 + nq * 32 + nt * 16 + lc;
                    if (vregion) {
                        // V: write directly to Vt[B,H,D,S]; 4 acc rows = contiguous s
                        int col4 = (int)col - 2 * D_MODEL;
                        int h = col4 >> 7, d = col4 & 127;
                        int b = (int)(row0 >> 11), s0 = (int)(row0 & 2047);
                        bf16x4 pv;
#pragma unroll
                        for (int rr = 0; rr < 4; ++rr) pv[rr] = (bf16)acc[mq][nq][mt][nt][rr];
                        *(bf16x4*)(Vt + ((size_t)(b * NH + h) * HD + d) * SEQ + s0) = pv;
                    } else {
#pragma unroll
                        for (int rr = 0; rr < 4; ++rr) {
                            float v = acc[mq][nq][mt][nt][rr];
                            if (OUTMODE == 1) ((float*)Cout)[(row0 + rr) * N + col] = v;
                            else              ((bf16*)Cout)[(row0 + rr) * N + col] = (bf16)v;
                        }
                    }
                }
}

// ---------------- Flash attention (unchanged from R5) ----------------
__global__ __launch_bounds__(256)
void flash_attn(const bf16* __restrict__ QKV, const bf16* __restrict__ Vt,
                bf16* __restrict__ O) {
    __shared__ __align__(16) bf16 Ks[2][64 * 128];   // [key][d], rows 256B
    __shared__ __align__(16) bf16 Vs[2][128 * 64];   // [d][key], rows 128B
    __shared__ __align__(16) bf16 p_lds[4][16 * 64]; // per-wave P[q][key], rows 128B

    const int bid = blockIdx.x;                   // 512
    const int lin = (bid & 7) * 64 + (bid >> 3);  // XCD-chunked
    const int bh = lin >> 4;
    const int jj = lin & 15;
    const int b = bh >> 4, h = bh & 15;

    const int tid = threadIdx.x;
    const int w = tid >> 6, l = tid & 63;
    const int lg = l >> 4, lc = l & 15;
    const int kswz = (lc & 7) << 4;
    char* pb = (char*)&p_lds[w][0];

    auto stageK = [&](int p, int kb) {
#pragma unroll
        for (int c = 0; c < 4; ++c) {
            int r = c * 16 + w * 4 + (l >> 4);
            int scb = ((l & 15) * 16) ^ ((r & 7) << 4);
            const bf16* g = QKV + ((size_t)(b * SEQ + kb * 64 + r)) * QKV_LD + D_MODEL + h * HD + (scb >> 1);
            gld16(&Ks[p][(c * 16 + w * 4) * 128], g);
        }
    };
    auto stageV = [&](int p, int kb) {
#pragma unroll
        for (int c = 0; c < 4; ++c) {
            int r = c * 32 + w * 8 + (l >> 3);
            int scb = ((l & 7) * 16) ^ ((r & 7) << 4);
            const bf16* g = Vt + ((size_t)bh * HD + r) * SEQ + kb * 64 + (scb >> 1);
            gld16(&Vs[p][(c * 32 + w * 8) * 64], g);
        }
    };

    int cur = 0;
#pragma unroll 1
    for (int ti = 0; ti < 2; ++ti) {
        const int qt = ti ? jj : (31 - jj);       // long tile first
        const int q0 = qt * 64 + w * 16;

        const bf16* qp = QKV + ((size_t)(b * SEQ + q0 + lc)) * QKV_LD + h * HD + lg * 8;
        bf16x8 qf[4];
#pragma unroll
        for (int kc = 0; kc < 4; ++kc) qf[kc] = *(const bf16x8*)(qp + kc * 32);

        f32x4 ctx[8] = {};
        float m_s = -INFINITY, l_s = 0.f;

        stageK(cur, 0);
        stageV(cur, 0);

        for (int kb = 0; kb <= qt; ++kb) {
            __syncthreads();
            if (kb < qt) { stageK(cur ^ 1, kb + 1); stageV(cur ^ 1, kb + 1); }

            const char* kbp = (const char*)&Ks[cur][0];
            f32x4 st[4] = {};
#pragma unroll
            for (int nf = 0; nf < 4; ++nf) {
                int krow = nf * 16 + lc;
#pragma unroll
                for (int kc = 0; kc < 4; ++kc) {
                    bf16x8 kf = *(const bf16x8*)(kbp + krow * 256 + ((kc * 64 + lg * 16) ^ kswz));
                    st[nf] = __builtin_amdgcn_mfma_f32_16x16x32_bf16(kf, qf[kc], st[nf], 0, 0, 0);
                }
            }

            if (kb == qt) {
                int q = q0 + lc;
#pragma unroll
                for (int nf = 0; nf < 4; ++nf) {
                    int key = kb * 64 + nf * 16 + lg * 4;
#pragma unroll
                    for (int r = 0; r < 4; ++r)
                        if (key + r > q) st[nf][r] = -INFINITY;
                }
            }

            float mx = -INFINITY;
#pragma unroll
            for (int nf = 0; nf < 4; ++nf)
#pragma unroll
                for (int r = 0; r < 4; ++r) mx = fmaxf(mx, st[nf][r]);
            mx = fmaxf(mx, __shfl_xor(mx, 16));
            mx = fmaxf(mx, __shfl_xor(mx, 32));
            float mi = fmaxf(m_s, mx);
            float scv = __expf(m_s - mi);
            m_s = mi;

            float rs = 0.f;
#pragma unroll
            for (int nf = 0; nf < 4; ++nf) {
                float p0 = __expf(st[nf][0] - mi);
                float p1 = __expf(st[nf][1] - mi);
                float p2 = __expf(st[nf][2] - mi);
                float p3 = __expf(st[nf][3] - mi);
                rs += (p0 + p1) + (p2 + p3);
                bf16x4 pv = { (bf16)p0, (bf16)p1, (bf16)p2, (bf16)p3 };
                *(bf16x4*)(pb + lc * 128 + ((nf * 32 + lg * 8) ^ kswz)) = pv;
            }
            rs += __shfl_xor(rs, 16);
            rs += __shfl_xor(rs, 32);
            l_s = l_s * scv + rs;

            float scvr[4];
#pragma unroll
            for (int r = 0; r < 4; ++r) scvr[r] = __shfl(scv, lg * 4 + r);
#pragma unroll
            for (int nd = 0; nd < 8; ++nd)
#pragma unroll
                for (int r = 0; r < 4; ++r) ctx[nd][r] *= scvr[r];

            asm volatile("s_waitcnt lgkmcnt(0)" ::: "memory");
            SBAR();
            bf16x8 pa0 = *(const bf16x8*)(pb + lc * 128 + ((lg * 16) ^ kswz));
            bf16x8 pa1 = *(const bf16x8*)(pb + lc * 128 + ((64 + lg * 16) ^ kswz));

            const char* vb = (const char*)&Vs[cur][0];
#pragma unroll
            for (int nd = 0; nd < 8; ++nd) {
                int vrow = nd * 16 + lc;
#pragma unroll
                for (int k2 = 0; k2 < 2; ++k2) {
                    bf16x8 vf = *(const bf16x8*)(vb + vrow * 128 + ((k2 * 64 + lg * 16) ^ kswz));
                    ctx[nd] = __builtin_amdgcn_mfma_f32_16x16x32_bf16(k2 ? pa1 : pa0, vf, ctx[nd], 0, 0, 0);
                }
            }
            cur ^= 1;
        }

        float lr[4];
#pragma unroll
        for (int r = 0; r < 4; ++r) lr[r] = 1.f / __shfl(l_s, lg * 4 + r);
#pragma unroll
        for (int nd = 0; nd < 8; ++nd)
#pragma unroll
            for (int r = 0; r < 4; ++r)
                O[((size_t)(b * SEQ + q0 + lg * 4 + r)) * D_MODEL + h * HD + nd * 16 + lc] =
                    (bf16)(ctx[nd][r] * lr[r]);
    }
}

// ---------------- launch ----------------
extern "C" void kernel_launch(void* const* d_in, const int* in_sizes, int n_in,
                              void* d_out, int out_size, void* d_ws, size_t ws_size,
                              hipStream_t stream) {
    const float* x  = (const float*)d_in[0];
    const float* Wq = (const float*)d_in[1];
    const float* Wk = (const float*)d_in[2];
    const float* Wv = (const float*)d_in[3];
    const float* Wo = (const float*)d_in[4];

    char* ws = (char*)d_ws;
    bf16* xb   = (bf16*)(ws + 0);            // 16 MB; reused as ctx after QKV GEMM
    bf16* wqkv = (bf16*)(ws + 16777216);     // 24 MB  [6144][2048]
    bf16* wob  = (bf16*)(ws + 41943040);     // 8 MB
    bf16* QKV  = (bf16*)(ws + 50331648);     // 48 MB  [4096][6144] (V region unused)
    bf16* Vtb  = (bf16*)(ws + 100663296);    // 16 MB  [B,H,D,S]
    float* cosd = (float*)(ws + 117440512);
    float* sind = (float*)(ws + 117964800);

    // fused convert: 25165824 elems -> contiguous xb|wqkv|wob
    cvt_all<<<25165824 / 1024, 256, 0, stream>>>(x, Wq, Wk, Wv, Wo, xb);

    rope_tables_k<<<(SEQ * 64) / 256, 256, 0, stream>>>(cosd, sind);

    // fused QKV projection: [4096,2048] x [6144,2048]^T -> QKV (Q,K) + Vt (V)
    // chunk dims (host-derived): nM=16,nN=24,cpx=48 -> chm=8,chn=6,ncn=4
    gemm8p<2><<<dim3(384), 512, 0, stream>>>(
        xb, wqkv, QKV, Vtb, BATCH * SEQ, QKV_LD, D_MODEL, 8, 6, 4);

    const float qscale = 0.08838834764831845f;  // 1/sqrt(128)
    rope_apply<<<(BATCH * SEQ * 1024) / 256, 256, 0, stream>>>(QKV,           cosd, sind, qscale, QKV_LD);
    rope_apply<<<(BATCH * SEQ * 1024) / 256, 256, 0, stream>>>(QKV + D_MODEL, cosd, sind, 1.0f,   QKV_LD);

    flash_attn<<<dim3(512), 256, 0, stream>>>(QKV, Vtb, xb /*ctx*/);

    // output projection: [4096,2048] x [2048,2048]^T -> d_out (f32)
    // nM=16,nN=8,cpx=16 -> chm=4,chn=4,ncn=2
    gemm8p<1><<<dim3(128), 512, 0, stream>>>(
        xb, wob, d_out, nullptr, BATCH * SEQ, D_MODEL, D_MODEL, 4, 4, 2);
}

// Round 8
// 284.155 us; speedup vs baseline: 1.0944x; 1.0336x over previous
//
#include <hip/hip_runtime.h>
#include <hip/hip_bf16.h>
#include <cstdint>
#include <cstddef>

typedef __bf16 bf16;
typedef __bf16 bf16x4 __attribute__((ext_vector_type(4)));
typedef __bf16 bf16x8 __attribute__((ext_vector_type(8)));
typedef float f32x4 __attribute__((ext_vector_type(4)));

#define D_MODEL 2048
#define SEQ     2048
#define NH      16
#define HD      128
#define BATCH   2
#define QKV_LD  6144

#define SBAR()  __builtin_amdgcn_sched_barrier(0)
#define HWBAR() do { SBAR(); __builtin_amdgcn_s_barrier(); SBAR(); } while (0)

// ---------------- async global->LDS 16B ----------------
__device__ __forceinline__ void gld16(void* lds, const void* g) {
    __builtin_amdgcn_global_load_lds(
        (const __attribute__((address_space(1))) unsigned int*)g,
        (__attribute__((address_space(3))) unsigned int*)lds,
        16, 0, 0);
}

// ---------------- fused fp32 -> bf16 convert (x, Wq, Wk, Wv, Wo) ----------------
__global__ __launch_bounds__(256) void cvt_all(const float* __restrict__ x,
                                               const float* __restrict__ Wq,
                                               const float* __restrict__ Wk,
                                               const float* __restrict__ Wv,
                                               const float* __restrict__ Wo,
                                               bf16* __restrict__ out) {
    int i = (blockIdx.x * 256 + threadIdx.x) * 4;  // 25165824 total elems
    const float* src;
    int off;
    if (i < 8388608) { src = x; off = i; }
    else {
        int j = i - 8388608;
        int seg = j >> 22;
        src = (seg == 0) ? Wq : (seg == 1) ? Wk : (seg == 2) ? Wv : Wo;
        off = j & 4194303;
    }
    float4 v = *(const float4*)(src + off);
    bf16* o = out + i;
    o[0] = (bf16)v.x; o[1] = (bf16)v.y; o[2] = (bf16)v.z; o[3] = (bf16)v.w;
}

// ---------------- RoPE tables (cos/sin, S x 64) ----------------
__global__ __launch_bounds__(256) void rope_tables_k(float* __restrict__ cosd,
                                                     float* __restrict__ sind) {
    int id = blockIdx.x * 256 + threadIdx.x;  // SEQ*64
    int s = id >> 6, d = id & 63;
    float freq = powf(10000.f, -(float)d * (1.f / 64.f));
    float a = (float)s * freq;
    float sn, c;
    sincosf(a, &sn, &c);
    cosd[id] = c;
    sind[id] = sn;
}

// ---------------- RoPE apply (in-place, row stride ld) ----------------
__global__ __launch_bounds__(256) void rope_apply(bf16* __restrict__ T,
                                                  const float* __restrict__ cosd,
                                                  const float* __restrict__ sind,
                                                  float scale, int ld) {
    int id = blockIdx.x * 256 + threadIdx.x;   // B*S*NH*64
    int row = id >> 10;                        // B*S
    int p = id & 1023;
    int h = p >> 6, d = p & 63;
    int s = row & (SEQ - 1);
    size_t base = (size_t)row * ld + h * HD + d;
    float x1 = (float)T[base];
    float x2 = (float)T[base + 64];
    float c = cosd[(s << 6) + d];
    float sn = sind[(s << 6) + d];
    T[base]      = (bf16)((x1 * c - x2 * sn) * scale);
    T[base + 64] = (bf16)((x2 * c + x1 * sn) * scale);
}

// ---------------- V transpose: [B,S,(ld)] head cols -> [B,H,D,S] ----------------
__global__ __launch_bounds__(256) void transpose_v(const bf16* __restrict__ V,
                                                   bf16* __restrict__ Vt, int ld) {
    __shared__ bf16 t[32][33];
    int s0 = blockIdx.x * 32;
    int d0 = blockIdx.y * 32;
    int bh = blockIdx.z;
    int b = bh >> 4, h = bh & 15;
    int tx = threadIdx.x & 31, ty = threadIdx.x >> 5;  // ty 0..7
#pragma unroll
    for (int i = 0; i < 32; i += 8)
        t[ty + i][tx] = V[((size_t)(b * SEQ + s0 + ty + i)) * ld + h * HD + d0 + tx];
    __syncthreads();
#pragma unroll
    for (int i = 0; i < 32; i += 8)
        Vt[((size_t)bh * HD + d0 + ty + i) * SEQ + s0 + tx] = t[tx][ty + i];
}

// ---------------- 256x256 8-phase NT GEMM (R5-exact + safe final drain) ----
template <int OUTF32>
__global__ __launch_bounds__(512, 2)
void gemm8p(const bf16* __restrict__ A, const bf16* __restrict__ B,
            void* __restrict__ Cout, int M, int N, int K) {
    __shared__ __align__(16) bf16 ldsAB[2][2][2][128 * 64];

    const int nN = N >> 8;
    const int nwg = gridDim.x;
    const int cpx = nwg >> 3;
    const int lin = (blockIdx.x & 7) * cpx + (blockIdx.x >> 3);
    const int m0 = (lin / nN) * 256, n0 = (lin % nN) * 256;

    const int tid = threadIdx.x;
    const int w = tid >> 6, l = tid & 63;
    const int wm = w >> 2, wn = w & 3;
    const int lg = l >> 4, lc = l & 15;
    const int swz = (lc & 7) << 4;
    const int NT = K >> 6;
    const int HMAX = NT * 4;

    f32x4 acc[2][2][4][2] = {};

    auto stage = [&](int H) {
        const int tau = H >> 2, h = H & 3;
        bf16* dst = &ldsAB[tau & 1][h >> 1][h & 1][0];
#pragma unroll
        for (int j = 0; j < 2; ++j) {
            int r = w * 8 + j * 64 + (l >> 3);
            int scb = ((l & 7) * 16) ^ ((r & 7) << 4);
            const bf16* g = (h < 2)
                ? A + (size_t)(m0 + (h & 1) * 128 + r) * K + tau * 64 + (scb >> 1)
                : B + (size_t)(n0 + (h & 1) * 128 + r) * K + tau * 64 + (scb >> 1);
            gld16(dst + (w * 8 + j * 64) * 64, g);
        }
    };

    stage(0); stage(1); stage(2); stage(3); stage(4);
    SBAR();
    asm volatile("s_waitcnt vmcnt(2)" ::: "memory");
    HWBAR();

    for (int t = 0; t < NT; ++t) {
        const int c = t & 1;
        const char* Ab = (const char*)&ldsAB[c][0][wm][0];
        const char* Bb = (const char*)&ldsAB[c][1][wn >> 1][0];
        const int brow0 = (wn & 1) * 64;
        bf16x8 Af[4][2], Bf[2][2][2];

        // ---- phase 0: (mq0, nq0) ----
#pragma unroll
        for (int mt = 0; mt < 4; ++mt)
#pragma unroll
            for (int ks = 0; ks < 2; ++ks)
                Af[mt][ks] = *(const bf16x8*)(Ab + (mt * 16 + lc) * 128 + ((ks * 64 + lg * 16) ^ swz));
#pragma unroll
        for (int nt = 0; nt < 2; ++nt)
#pragma unroll
            for (int ks = 0; ks < 2; ++ks)
                Bf[0][nt][ks] = *(const bf16x8*)(Bb + (brow0 + nt * 16 + lc) * 128 + ((ks * 64 + lg * 16) ^ swz));
        { int H = 4 * t + 5; if (H < HMAX) stage(H); }
        HWBAR();
        __builtin_amdgcn_s_setprio(1);
#pragma unroll
        for (int mt = 0; mt < 4; ++mt)
#pragma unroll
            for (int nt = 0; nt < 2; ++nt)
#pragma unroll
                for (int ks = 0; ks < 2; ++ks)
                    acc[0][0][mt][nt] = __builtin_amdgcn_mfma_f32_16x16x32_bf16(Af[mt][ks], Bf[0][nt][ks], acc[0][0][mt][nt], 0, 0, 0);
        __builtin_amdgcn_s_setprio(0);
        HWBAR();

        // ---- phase 1: (mq0, nq1) ----
#pragma unroll
        for (int nt = 0; nt < 2; ++nt)
#pragma unroll
            for (int ks = 0; ks < 2; ++ks)
                Bf[1][nt][ks] = *(const bf16x8*)(Bb + (brow0 + 32 + nt * 16 + lc) * 128 + ((ks * 64 + lg * 16) ^ swz));
        { int H = 4 * t + 6; if (H < HMAX) stage(H); }
        HWBAR();
        __builtin_amdgcn_s_setprio(1);
#pragma unroll
        for (int mt = 0; mt < 4; ++mt)
#pragma unroll
            for (int nt = 0; nt < 2; ++nt)
#pragma unroll
                for (int ks = 0; ks < 2; ++ks)
                    acc[0][1][mt][nt] = __builtin_amdgcn_mfma_f32_16x16x32_bf16(Af[mt][ks], Bf[1][nt][ks], acc[0][1][mt][nt], 0, 0, 0);
        __builtin_amdgcn_s_setprio(0);
        HWBAR();

        // ---- phase 2: (mq1, nq0) ----
#pragma unroll
        for (int mt = 0; mt < 4; ++mt)
#pragma unroll
            for (int ks = 0; ks < 2; ++ks)
                Af[mt][ks] = *(const bf16x8*)(Ab + (64 + mt * 16 + lc) * 128 + ((ks * 64 + lg * 16) ^ swz));
        { int H = 4 * t + 7; if (H < HMAX) stage(H); }
        HWBAR();
        __builtin_amdgcn_s_setprio(1);
#pragma unroll
        for (int mt = 0; mt < 4; ++mt)
#pragma unroll
            for (int nt = 0; nt < 2; ++nt)
#pragma unroll
                for (int ks = 0; ks < 2; ++ks)
                    acc[1][0][mt][nt] = __builtin_amdgcn_mfma_f32_16x16x32_bf16(Af[mt][ks], Bf[0][nt][ks], acc[1][0][mt][nt], 0, 0, 0);
        __builtin_amdgcn_s_setprio(0);
        HWBAR();

        // ---- phase 3: (mq1, nq1) ----
        { int H = 4 * t + 8; if (H < HMAX) stage(H); }
        HWBAR();
        __builtin_amdgcn_s_setprio(1);
#pragma unroll
        for (int mt = 0; mt < 4; ++mt)
#pragma unroll
            for (int nt = 0; nt < 2; ++nt)
#pragma unroll
                for (int ks = 0; ks < 2; ++ks)
                    acc[1][1][mt][nt] = __builtin_amdgcn_mfma_f32_16x16x32_bf16(Af[mt][ks], Bf[1][nt][ks], acc[1][1][mt][nt], 0, 0, 0);
        __builtin_amdgcn_s_setprio(0);
        SBAR();
        if (t + 2 < NT) asm volatile("s_waitcnt vmcnt(2)" ::: "memory");
        else            asm volatile("s_waitcnt vmcnt(0)" ::: "memory");
        HWBAR();
    }

    // ---- epilogue ----
#pragma unroll
    for (int mq = 0; mq < 2; ++mq)
#pragma unroll
        for (int nq = 0; nq < 2; ++nq)
#pragma unroll
            for (int mt = 0; mt < 4; ++mt)
#pragma unroll
                for (int nt = 0; nt < 2; ++nt)
#pragma unroll
                    for (int rr = 0; rr < 4; ++rr) {
                        size_t row = (size_t)m0 + wm * 128 + mq * 64 + mt * 16 + lg * 4 + rr;
                        size_t col = (size_t)n0 + wn * 64 + nq * 32 + nt * 16 + lc;
                        float v = acc[mq][nq][mt][nt][rr];
                        if (OUTF32) ((float*)Cout)[row * N + col] = v;
                        else        ((bf16*)Cout)[row * N + col] = (bf16)v;
                    }
}

// ---------------- 128x128 NT GEMM (m97 structure, proven in R2) ----------------
// 256 thr = 4 waves (2x2), BK=32, double-buffered LDS via global_load_lds.
template <int OUTF32>
__global__ __launch_bounds__(256)
void gemm_nt(const bf16* __restrict__ A, const bf16* __restrict__ B,
             void* __restrict__ Cout, int M, int N, int K) {
    __shared__ bf16 As[2][128 * 32];
    __shared__ bf16 Bs[2][128 * 32];
    const int m0 = blockIdx.y * 128, n0 = blockIdx.x * 128;
    const int tid = threadIdx.x;
    const int w = tid >> 6, l = tid & 63;
    const int wr = w >> 1, wc = w & 1;
    const int lg = l >> 4, lc = l & 15;

    f32x4 acc[4][4] = {};
    const int NT = K >> 5;

    auto stage = [&](int p, int t) {
#pragma unroll
        for (int c = 0; c < 2; ++c) {
            int reg = w * 2 + c;
            const bf16* ga = A + (size_t)(m0 + reg * 16 + (l >> 2)) * K + t * 32 + (l & 3) * 8;
            const bf16* gb = B + (size_t)(n0 + reg * 16 + (l >> 2)) * K + t * 32 + (l & 3) * 8;
            gld16(&As[p][reg * 512], ga);
            gld16(&Bs[p][reg * 512], gb);
        }
    };

    stage(0, 0);
    int cur = 0;
    for (int t = 0; t < NT; ++t) {
        __syncthreads();
        if (t + 1 < NT) stage(cur ^ 1, t + 1);
        bf16x8 af[4], bfr[4];
#pragma unroll
        for (int m = 0; m < 4; ++m)
            af[m] = *(const bf16x8*)&As[cur][(wr * 64 + m * 16 + lc) * 32 + lg * 8];
#pragma unroll
        for (int n = 0; n < 4; ++n)
            bfr[n] = *(const bf16x8*)&Bs[cur][(wc * 64 + n * 16 + lc) * 32 + lg * 8];
#pragma unroll
        for (int m = 0; m < 4; ++m)
#pragma unroll
            for (int n = 0; n < 4; ++n)
                acc[m][n] = __builtin_amdgcn_mfma_f32_16x16x32_bf16(af[m], bfr[n], acc[m][n], 0, 0, 0);
        cur ^= 1;
    }

#pragma unroll
    for (int m = 0; m < 4; ++m)
#pragma unroll
        for (int n = 0; n < 4; ++n)
#pragma unroll
            for (int r = 0; r < 4; ++r) {
                size_t row = (size_t)m0 + wr * 64 + m * 16 + lg * 4 + r;
                size_t col = (size_t)n0 + wc * 64 + n * 16 + lc;
                float v = acc[m][n][r];
                if (OUTF32)
                    ((float*)Cout)[row * N + col] = v;
                else
                    ((bf16*)Cout)[row * N + col] = (bf16)v;
            }
}

// ---------------- Flash attention (unchanged from R5) ----------------
__global__ __launch_bounds__(256)
void flash_attn(const bf16* __restrict__ QKV, const bf16* __restrict__ Vt,
                bf16* __restrict__ O) {
    __shared__ __align__(16) bf16 Ks[2][64 * 128];   // [key][d], rows 256B
    __shared__ __align__(16) bf16 Vs[2][128 * 64];   // [d][key], rows 128B
    __shared__ __align__(16) bf16 p_lds[4][16 * 64]; // per-wave P[q][key], rows 128B

    const int bid = blockIdx.x;                   // 512
    const int lin = (bid & 7) * 64 + (bid >> 3);  // XCD-chunked
    const int bh = lin >> 4;
    const int jj = lin & 15;
    const int b = bh >> 4, h = bh & 15;

    const int tid = threadIdx.x;
    const int w = tid >> 6, l = tid & 63;
    const int lg = l >> 4, lc = l & 15;
    const int kswz = (lc & 7) << 4;
    char* pb = (char*)&p_lds[w][0];

    auto stageK = [&](int p, int kb) {
#pragma unroll
        for (int c = 0; c < 4; ++c) {
            int r = c * 16 + w * 4 + (l >> 4);
            int scb = ((l & 15) * 16) ^ ((r & 7) << 4);
            const bf16* g = QKV + ((size_t)(b * SEQ + kb * 64 + r)) * QKV_LD + D_MODEL + h * HD + (scb >> 1);
            gld16(&Ks[p][(c * 16 + w * 4) * 128], g);
        }
    };
    auto stageV = [&](int p, int kb) {
#pragma unroll
        for (int c = 0; c < 4; ++c) {
            int r = c * 32 + w * 8 + (l >> 3);
            int scb = ((l & 7) * 16) ^ ((r & 7) << 4);
            const bf16* g = Vt + ((size_t)bh * HD + r) * SEQ + kb * 64 + (scb >> 1);
            gld16(&Vs[p][(c * 32 + w * 8) * 64], g);
        }
    };

    int cur = 0;
#pragma unroll 1
    for (int ti = 0; ti < 2; ++ti) {
        const int qt = ti ? jj : (31 - jj);       // long tile first
        const int q0 = qt * 64 + w * 16;

        const bf16* qp = QKV + ((size_t)(b * SEQ + q0 + lc)) * QKV_LD + h * HD + lg * 8;
        bf16x8 qf[4];
#pragma unroll
        for (int kc = 0; kc < 4; ++kc) qf[kc] = *(const bf16x8*)(qp + kc * 32);

        f32x4 ctx[8] = {};
        float m_s = -INFINITY, l_s = 0.f;

        stageK(cur, 0);
        stageV(cur, 0);

        for (int kb = 0; kb <= qt; ++kb) {
            __syncthreads();
            if (kb < qt) { stageK(cur ^ 1, kb + 1); stageV(cur ^ 1, kb + 1); }

            const char* kbp = (const char*)&Ks[cur][0];
            f32x4 st[4] = {};
#pragma unroll
            for (int nf = 0; nf < 4; ++nf) {
                int krow = nf * 16 + lc;
#pragma unroll
                for (int kc = 0; kc < 4; ++kc) {
                    bf16x8 kf = *(const bf16x8*)(kbp + krow * 256 + ((kc * 64 + lg * 16) ^ kswz));
                    st[nf] = __builtin_amdgcn_mfma_f32_16x16x32_bf16(kf, qf[kc], st[nf], 0, 0, 0);
                }
            }

            if (kb == qt) {
                int q = q0 + lc;
#pragma unroll
                for (int nf = 0; nf < 4; ++nf) {
                    int key = kb * 64 + nf * 16 + lg * 4;
#pragma unroll
                    for (int r = 0; r < 4; ++r)
                        if (key + r > q) st[nf][r] = -INFINITY;
                }
            }

            float mx = -INFINITY;
#pragma unroll
            for (int nf = 0; nf < 4; ++nf)
#pragma unroll
                for (int r = 0; r < 4; ++r) mx = fmaxf(mx, st[nf][r]);
            mx = fmaxf(mx, __shfl_xor(mx, 16));
            mx = fmaxf(mx, __shfl_xor(mx, 32));
            float mi = fmaxf(m_s, mx);
            float scv = __expf(m_s - mi);
            m_s = mi;

            float rs = 0.f;
#pragma unroll
            for (int nf = 0; nf < 4; ++nf) {
                float p0 = __expf(st[nf][0] - mi);
                float p1 = __expf(st[nf][1] - mi);
                float p2 = __expf(st[nf][2] - mi);
                float p3 = __expf(st[nf][3] - mi);
                rs += (p0 + p1) + (p2 + p3);
                bf16x4 pv = { (bf16)p0, (bf16)p1, (bf16)p2, (bf16)p3 };
                *(bf16x4*)(pb + lc * 128 + ((nf * 32 + lg * 8) ^ kswz)) = pv;
            }
            rs += __shfl_xor(rs, 16);
            rs += __shfl_xor(rs, 32);
            l_s = l_s * scv + rs;

            float scvr[4];
#pragma unroll
            for (int r = 0; r < 4; ++r) scvr[r] = __shfl(scv, lg * 4 + r);
#pragma unroll
            for (int nd = 0; nd < 8; ++nd)
#pragma unroll
                for (int r = 0; r < 4; ++r) ctx[nd][r] *= scvr[r];

            asm volatile("s_waitcnt lgkmcnt(0)" ::: "memory");
            SBAR();
            bf16x8 pa0 = *(const bf16x8*)(pb + lc * 128 + ((lg * 16) ^ kswz));
            bf16x8 pa1 = *(const bf16x8*)(pb + lc * 128 + ((64 + lg * 16) ^ kswz));

            const char* vb = (const char*)&Vs[cur][0];
#pragma unroll
            for (int nd = 0; nd < 8; ++nd) {
                int vrow = nd * 16 + lc;
#pragma unroll
                for (int k2 = 0; k2 < 2; ++k2) {
                    bf16x8 vf = *(const bf16x8*)(vb + vrow * 128 + ((k2 * 64 + lg * 16) ^ kswz));
                    ctx[nd] = __builtin_amdgcn_mfma_f32_16x16x32_bf16(k2 ? pa1 : pa0, vf, ctx[nd], 0, 0, 0);
                }
            }
            cur ^= 1;
        }

        float lr[4];
#pragma unroll
        for (int r = 0; r < 4; ++r) lr[r] = 1.f / __shfl(l_s, lg * 4 + r);
#pragma unroll
        for (int nd = 0; nd < 8; ++nd)
#pragma unroll
            for (int r = 0; r < 4; ++r)
                O[((size_t)(b * SEQ + q0 + lg * 4 + r)) * D_MODEL + h * HD + nd * 16 + lc] =
                    (bf16)(ctx[nd][r] * lr[r]);
    }
}

// ---------------- launch ----------------
extern "C" void kernel_launch(void* const* d_in, const int* in_sizes, int n_in,
                              void* d_out, int out_size, void* d_ws, size_t ws_size,
                              hipStream_t stream) {
    const float* x  = (const float*)d_in[0];
    const float* Wq = (const float*)d_in[1];
    const float* Wk = (const float*)d_in[2];
    const float* Wv = (const float*)d_in[3];
    const float* Wo = (const float*)d_in[4];

    char* ws = (char*)d_ws;
    bf16* xb   = (bf16*)(ws + 0);            // 16 MB; reused as ctx after QKV GEMM
    bf16* wqkv = (bf16*)(ws + 16777216);     // 24 MB  [6144][2048]
    bf16* wob  = (bf16*)(ws + 41943040);     // 8 MB
    bf16* QKV  = (bf16*)(ws + 50331648);     // 48 MB  [4096][6144]
    bf16* Vtb  = (bf16*)(ws + 100663296);    // 16 MB  [B,H,D,S]
    float* cosd = (float*)(ws + 117440512);
    float* sind = (float*)(ws + 117964800);

    // fused convert: 25165824 elems -> contiguous xb|wqkv|wob
    cvt_all<<<25165824 / 1024, 256, 0, stream>>>(x, Wq, Wk, Wv, Wo, xb);

    rope_tables_k<<<(SEQ * 64) / 256, 256, 0, stream>>>(cosd, sind);

    // fused QKV projection: [4096,2048] x [6144,2048]^T -> [4096,6144]
    gemm8p<0><<<dim3(384), 512, 0, stream>>>(
        xb, wqkv, QKV, BATCH * SEQ, QKV_LD, D_MODEL);

    const float qscale = 0.08838834764831845f;  // 1/sqrt(128)
    rope_apply<<<(BATCH * SEQ * 1024) / 256, 256, 0, stream>>>(QKV,           cosd, sind, qscale, QKV_LD);
    rope_apply<<<(BATCH * SEQ * 1024) / 256, 256, 0, stream>>>(QKV + D_MODEL, cosd, sind, 1.0f,   QKV_LD);

    transpose_v<<<dim3(SEQ / 32, HD / 32, BATCH * NH), 256, 0, stream>>>(QKV + 2 * D_MODEL, Vtb, QKV_LD);

    flash_attn<<<dim3(512), 256, 0, stream>>>(QKV, Vtb, xb /*ctx*/);

    // output projection: [4096,2048] x [2048,2048]^T -> d_out (f32), 512 blocks 2/CU
    gemm_nt<1><<<dim3(D_MODEL / 128, (BATCH * SEQ) / 128), 256, 0, stream>>>(
        xb, wob, d_out, BATCH * SEQ, D_MODEL, D_MODEL);
}

// Round 11
// 276.331 us; speedup vs baseline: 1.1254x; 1.0283x over previous
//
#include <hip/hip_runtime.h>
#include <hip/hip_bf16.h>
#include <cstdint>
#include <cstddef>

typedef __bf16 bf16;
typedef __bf16 bf16x4 __attribute__((ext_vector_type(4)));
typedef __bf16 bf16x8 __attribute__((ext_vector_type(8)));
typedef float f32x4 __attribute__((ext_vector_type(4)));

#define D_MODEL 2048
#define SEQ     2048
#define NH      16
#define HD      128
#define BATCH   2
#define QKV_LD  6144

#define SBAR()  __builtin_amdgcn_sched_barrier(0)
#define HWBAR() do { SBAR(); __builtin_amdgcn_s_barrier(); SBAR(); } while (0)

// ---------------- async global->LDS 16B ----------------
__device__ __forceinline__ void gld16(void* lds, const void* g) {
    __builtin_amdgcn_global_load_lds(
        (const __attribute__((address_space(1))) unsigned int*)g,
        (__attribute__((address_space(3))) unsigned int*)lds,
        16, 0, 0);
}

// ---------------- fused fp32 -> bf16 convert (x, Wq, Wk, Wv, Wo) ----------------
__global__ __launch_bounds__(256) void cvt_all(const float* __restrict__ x,
                                               const float* __restrict__ Wq,
                                               const float* __restrict__ Wk,
                                               const float* __restrict__ Wv,
                                               const float* __restrict__ Wo,
                                               bf16* __restrict__ out) {
    int i = (blockIdx.x * 256 + threadIdx.x) * 4;  // 25165824 total elems
    const float* src;
    int off;
    if (i < 8388608) { src = x; off = i; }
    else {
        int j = i - 8388608;
        int seg = j >> 22;
        src = (seg == 0) ? Wq : (seg == 1) ? Wk : (seg == 2) ? Wv : Wo;
        off = j & 4194303;
    }
    float4 v = *(const float4*)(src + off);
    bf16* o = out + i;
    o[0] = (bf16)v.x; o[1] = (bf16)v.y; o[2] = (bf16)v.z; o[3] = (bf16)v.w;
}

// ---------------- RoPE tables (cos/sin, S x 64) ----------------
__global__ __launch_bounds__(256) void rope_tables_k(float* __restrict__ cosd,
                                                     float* __restrict__ sind) {
    int id = blockIdx.x * 256 + threadIdx.x;  // SEQ*64
    int s = id >> 6, d = id & 63;
    float freq = powf(10000.f, -(float)d * (1.f / 64.f));
    float a = (float)s * freq;
    float sn, c;
    sincosf(a, &sn, &c);
    cosd[id] = c;
    sind[id] = sn;
}

// ---------------- RoPE apply (in-place, row stride ld) ----------------
__global__ __launch_bounds__(256) void rope_apply(bf16* __restrict__ T,
                                                  const float* __restrict__ cosd,
                                                  const float* __restrict__ sind,
                                                  float scale, int ld) {
    int id = blockIdx.x * 256 + threadIdx.x;   // B*S*NH*64
    int row = id >> 10;                        // B*S
    int p = id & 1023;
    int h = p >> 6, d = p & 63;
    int s = row & (SEQ - 1);
    size_t base = (size_t)row * ld + h * HD + d;
    float x1 = (float)T[base];
    float x2 = (float)T[base + 64];
    float c = cosd[(s << 6) + d];
    float sn = sind[(s << 6) + d];
    T[base]      = (bf16)((x1 * c - x2 * sn) * scale);
    T[base + 64] = (bf16)((x2 * c + x1 * sn) * scale);
}

// ---------------- V transpose: [B,S,(ld)] head cols -> [B,H,D,S] ----------------
__global__ __launch_bounds__(256) void transpose_v(const bf16* __restrict__ V,
                                                   bf16* __restrict__ Vt, int ld) {
    __shared__ bf16 t[32][33];
    int s0 = blockIdx.x * 32;
    int d0 = blockIdx.y * 32;
    int bh = blockIdx.z;
    int b = bh >> 4, h = bh & 15;
    int tx = threadIdx.x & 31, ty = threadIdx.x >> 5;  // ty 0..7
#pragma unroll
    for (int i = 0; i < 32; i += 8)
        t[ty + i][tx] = V[((size_t)(b * SEQ + s0 + ty + i)) * ld + h * HD + d0 + tx];
    __syncthreads();
#pragma unroll
    for (int i = 0; i < 32; i += 8)
        Vt[((size_t)bh * HD + d0 + ty + i) * SEQ + s0 + tx] = t[tx][ty + i];
}

// ---------------- 128x256 NT GEMM, 2-phase pipelined ----------------
// C[M,N] = A[M,K] * B[N,K]^T. 512 thr = 8 waves (2m x 4n), per-wave 64x64,
// BK=64, 96 KiB LDS double-buffered, row-XOR swizzle, counted vmcnt:
// B staged 1 tile ahead (ph0:B0, ph1:B1), A staged 2 tiles ahead (ph1).
template <int OUTF32>
__global__ __launch_bounds__(512, 2)
void gemm128(const bf16* __restrict__ A, const bf16* __restrict__ B,
             void* __restrict__ Cout, int M, int N, int K) {
    __shared__ __align__(16) bf16 ldsA[2][128 * 64];
    __shared__ __align__(16) bf16 ldsB[2][2][128 * 64];

    const int nN = N >> 8;
    const int cpx = gridDim.x >> 3;
    const int lin = (blockIdx.x & 7) * cpx + (blockIdx.x >> 3);  // XCD-chunked
    const int m0 = (lin / nN) * 128, n0 = (lin % nN) * 256;

    const int tid = threadIdx.x;
    const int w = tid >> 6, l = tid & 63;
    const int wm = w >> 2, wn = w & 3;
    const int lg = l >> 4, lc = l & 15;
    const int swz = (lc & 7) << 4;
    const int NT = K >> 6;

    f32x4 acc[2][4][2] = {};   // [nq][mt][nt]

    auto stageA = [&](int tau) {
        bf16* dst = &ldsA[tau & 1][0];
#pragma unroll
        for (int j = 0; j < 2; ++j) {
            int r = w * 16 + j * 8 + (l >> 3);
            int scb = ((l & 7) * 16) ^ ((r & 7) << 4);
            gld16(dst + (w * 16 + j * 8) * 64, A + (size_t)(m0 + r) * K + tau * 64 + (scb >> 1));
        }
    };
    auto stageB = [&](int tau, int u) {
        bf16* dst = &ldsB[tau & 1][u][0];
#pragma unroll
        for (int j = 0; j < 2; ++j) {
            int r = w * 16 + j * 8 + (l >> 3);
            int scb = ((l & 7) * 16) ^ ((r & 7) << 4);
            gld16(dst + (w * 16 + j * 8) * 64, B + (size_t)(n0 + u * 128 + r) * K + tau * 64 + (scb >> 1));
        }
    };

    // prologue: tile0 fully + A(1); tile0 resident, A(1) in flight
    stageA(0); stageB(0, 0); stageB(0, 1); stageA(1);
    SBAR();
    asm volatile("s_waitcnt vmcnt(2)" ::: "memory");
    HWBAR();

    for (int t = 0; t < NT; ++t) {
        const int c = t & 1;
        const char* Ab = (const char*)&ldsA[c][0];
        const char* Bb = (const char*)&ldsB[c][wn >> 1][0];
        const int brow0 = (wn & 1) * 64;
        bf16x8 Af[4][2], Bf[2][2];

        // ---- phase 0 (nq0): read A + B(nq0); stage B0(t+1) ----
#pragma unroll
        for (int mt = 0; mt < 4; ++mt)
#pragma unroll
            for (int ks = 0; ks < 2; ++ks)
                Af[mt][ks] = *(const bf16x8*)(Ab + (wm * 64 + mt * 16 + lc) * 128 + ((ks * 64 + lg * 16) ^ swz));
#pragma unroll
        for (int nt = 0; nt < 2; ++nt)
#pragma unroll
            for (int ks = 0; ks < 2; ++ks)
                Bf[nt][ks] = *(const bf16x8*)(Bb + (brow0 + nt * 16 + lc) * 128 + ((ks * 64 + lg * 16) ^ swz));
        if (t + 1 < NT) stageB(t + 1, 0);
        HWBAR();
        __builtin_amdgcn_s_setprio(1);
#pragma unroll
        for (int mt = 0; mt < 4; ++mt)
#pragma unroll
            for (int nt = 0; nt < 2; ++nt)
#pragma unroll
                for (int ks = 0; ks < 2; ++ks)
                    acc[0][mt][nt] = __builtin_amdgcn_mfma_f32_16x16x32_bf16(Af[mt][ks], Bf[nt][ks], acc[0][mt][nt], 0, 0, 0);
        __builtin_amdgcn_s_setprio(0);
        HWBAR();

        // ---- phase 1 (nq1): read B(nq1); stage B1(t+1) + A(t+2) ----
#pragma unroll
        for (int nt = 0; nt < 2; ++nt)
#pragma unroll
            for (int ks = 0; ks < 2; ++ks)
                Bf[nt][ks] = *(const bf16x8*)(Bb + (brow0 + 32 + nt * 16 + lc) * 128 + ((ks * 64 + lg * 16) ^ swz));
        if (t + 1 < NT) stageB(t + 1, 1);
        if (t + 2 < NT) stageA(t + 2);
        HWBAR();
        __builtin_amdgcn_s_setprio(1);
#pragma unroll
        for (int mt = 0; mt < 4; ++mt)
#pragma unroll
            for (int nt = 0; nt < 2; ++nt)
#pragma unroll
                for (int ks = 0; ks < 2; ++ks)
                    acc[1][mt][nt] = __builtin_amdgcn_mfma_f32_16x16x32_bf16(Af[mt][ks], Bf[nt][ks], acc[1][mt][nt], 0, 0, 0);
        __builtin_amdgcn_s_setprio(0);
        SBAR();
        if (t + 2 < NT) asm volatile("s_waitcnt vmcnt(2)" ::: "memory");
        else            asm volatile("s_waitcnt vmcnt(0)" ::: "memory");
        HWBAR();
    }

    // ---- epilogue ----
#pragma unroll
    for (int nq = 0; nq < 2; ++nq)
#pragma unroll
        for (int mt = 0; mt < 4; ++mt)
#pragma unroll
            for (int nt = 0; nt < 2; ++nt)
#pragma unroll
                for (int rr = 0; rr < 4; ++rr) {
                    size_t row = (size_t)m0 + wm * 64 + mt * 16 + lg * 4 + rr;
                    size_t col = (size_t)n0 + wn * 64 + nq * 32 + nt * 16 + lc;
                    float v = acc[nq][mt][nt][rr];
                    if (OUTF32) ((float*)Cout)[row * N + col] = v;
                    else        ((bf16*)Cout)[row * N + col] = (bf16)v;
                }
}

// ---------------- Flash attention (unchanged from R5/R8) ----------------
__global__ __launch_bounds__(256)
void flash_attn(const bf16* __restrict__ QKV, const bf16* __restrict__ Vt,
                bf16* __restrict__ O) {
    __shared__ __align__(16) bf16 Ks[2][64 * 128];   // [key][d], rows 256B
    __shared__ __align__(16) bf16 Vs[2][128 * 64];   // [d][key], rows 128B
    __shared__ __align__(16) bf16 p_lds[4][16 * 64]; // per-wave P[q][key], rows 128B

    const int bid = blockIdx.x;                   // 512
    const int lin = (bid & 7) * 64 + (bid >> 3);  // XCD-chunked
    const int bh = lin >> 4;
    const int jj = lin & 15;
    const int b = bh >> 4, h = bh & 15;

    const int tid = threadIdx.x;
    const int w = tid >> 6, l = tid & 63;
    const int lg = l >> 4, lc = l & 15;
    const int kswz = (lc & 7) << 4;
    char* pb = (char*)&p_lds[w][0];

    auto stageK = [&](int p, int kb) {
#pragma unroll
        for (int c = 0; c < 4; ++c) {
            int r = c * 16 + w * 4 + (l >> 4);
            int scb = ((l & 15) * 16) ^ ((r & 7) << 4);
            const bf16* g = QKV + ((size_t)(b * SEQ + kb * 64 + r)) * QKV_LD + D_MODEL + h * HD + (scb >> 1);
            gld16(&Ks[p][(c * 16 + w * 4) * 128], g);
        }
    };
    auto stageV = [&](int p, int kb) {
#pragma unroll
        for (int c = 0; c < 4; ++c) {
            int r = c * 32 + w * 8 + (l >> 3);
            int scb = ((l & 7) * 16) ^ ((r & 7) << 4);
            const bf16* g = Vt + ((size_t)bh * HD + r) * SEQ + kb * 64 + (scb >> 1);
            gld16(&Vs[p][(c * 32 + w * 8) * 64], g);
        }
    };

    int cur = 0;
#pragma unroll 1
    for (int ti = 0; ti < 2; ++ti) {
        const int qt = ti ? jj : (31 - jj);       // long tile first
        const int q0 = qt * 64 + w * 16;

        const bf16* qp = QKV + ((size_t)(b * SEQ + q0 + lc)) * QKV_LD + h * HD + lg * 8;
        bf16x8 qf[4];
#pragma unroll
        for (int kc = 0; kc < 4; ++kc) qf[kc] = *(const bf16x8*)(qp + kc * 32);

        f32x4 ctx[8] = {};
        float m_s = -INFINITY, l_s = 0.f;

        stageK(cur, 0);
        stageV(cur, 0);

        for (int kb = 0; kb <= qt; ++kb) {
            __syncthreads();
            if (kb < qt) { stageK(cur ^ 1, kb + 1); stageV(cur ^ 1, kb + 1); }

            const char* kbp = (const char*)&Ks[cur][0];
            f32x4 st[4] = {};
#pragma unroll
            for (int nf = 0; nf < 4; ++nf) {
                int krow = nf * 16 + lc;
#pragma unroll
                for (int kc = 0; kc < 4; ++kc) {
                    bf16x8 kf = *(const bf16x8*)(kbp + krow * 256 + ((kc * 64 + lg * 16) ^ kswz));
                    st[nf] = __builtin_amdgcn_mfma_f32_16x16x32_bf16(kf, qf[kc], st[nf], 0, 0, 0);
                }
            }

            if (kb == qt) {
                int q = q0 + lc;
#pragma unroll
                for (int nf = 0; nf < 4; ++nf) {
                    int key = kb * 64 + nf * 16 + lg * 4;
#pragma unroll
                    for (int r = 0; r < 4; ++r)
                        if (key + r > q) st[nf][r] = -INFINITY;
                }
            }

            float mx = -INFINITY;
#pragma unroll
            for (int nf = 0; nf < 4; ++nf)
#pragma unroll
                for (int r = 0; r < 4; ++r) mx = fmaxf(mx, st[nf][r]);
            mx = fmaxf(mx, __shfl_xor(mx, 16));
            mx = fmaxf(mx, __shfl_xor(mx, 32));
            float mi = fmaxf(m_s, mx);
            float scv = __expf(m_s - mi);
            m_s = mi;

            float rs = 0.f;
#pragma unroll
            for (int nf = 0; nf < 4; ++nf) {
                float p0 = __expf(st[nf][0] - mi);
                float p1 = __expf(st[nf][1] - mi);
                float p2 = __expf(st[nf][2] - mi);
                float p3 = __expf(st[nf][3] - mi);
                rs += (p0 + p1) + (p2 + p3);
                bf16x4 pv = { (bf16)p0, (bf16)p1, (bf16)p2, (bf16)p3 };
                *(bf16x4*)(pb + lc * 128 + ((nf * 32 + lg * 8) ^ kswz)) = pv;
            }
            rs += __shfl_xor(rs, 16);
            rs += __shfl_xor(rs, 32);
            l_s = l_s * scv + rs;

            float scvr[4];
#pragma unroll
            for (int r = 0; r < 4; ++r) scvr[r] = __shfl(scv, lg * 4 + r);
#pragma unroll
            for (int nd = 0; nd < 8; ++nd)
#pragma unroll
                for (int r = 0; r < 4; ++r) ctx[nd][r] *= scvr[r];

            asm volatile("s_waitcnt lgkmcnt(0)" ::: "memory");
            SBAR();
            bf16x8 pa0 = *(const bf16x8*)(pb + lc * 128 + ((lg * 16) ^ kswz));
            bf16x8 pa1 = *(const bf16x8*)(pb + lc * 128 + ((64 + lg * 16) ^ kswz));

            const char* vb = (const char*)&Vs[cur][0];
#pragma unroll
            for (int nd = 0; nd < 8; ++nd) {
                int vrow = nd * 16 + lc;
#pragma unroll
                for (int k2 = 0; k2 < 2; ++k2) {
                    bf16x8 vf = *(const bf16x8*)(vb + vrow * 128 + ((k2 * 64 + lg * 16) ^ kswz));
                    ctx[nd] = __builtin_amdgcn_mfma_f32_16x16x32_bf16(k2 ? pa1 : pa0, vf, ctx[nd], 0, 0, 0);
                }
            }
            cur ^= 1;
        }

        float lr[4];
#pragma unroll
        for (int r = 0; r < 4; ++r) lr[r] = 1.f / __shfl(l_s, lg * 4 + r);
#pragma unroll
        for (int nd = 0; nd < 8; ++nd)
#pragma unroll
            for (int r = 0; r < 4; ++r)
                O[((size_t)(b * SEQ + q0 + lg * 4 + r)) * D_MODEL + h * HD + nd * 16 + lc] =
                    (bf16)(ctx[nd][r] * lr[r]);
    }
}

// ---------------- launch ----------------
extern "C" void kernel_launch(void* const* d_in, const int* in_sizes, int n_in,
                              void* d_out, int out_size, void* d_ws, size_t ws_size,
                              hipStream_t stream) {
    const float* x  = (const float*)d_in[0];
    const float* Wq = (const float*)d_in[1];
    const float* Wk = (const float*)d_in[2];
    const float* Wv = (const float*)d_in[3];
    const float* Wo = (const float*)d_in[4];

    char* ws = (char*)d_ws;
    bf16* xb   = (bf16*)(ws + 0);            // 16 MB; reused as ctx after QKV GEMM
    bf16* wqkv = (bf16*)(ws + 16777216);     // 24 MB  [6144][2048]
    bf16* wob  = (bf16*)(ws + 41943040);     // 8 MB
    bf16* QKV  = (bf16*)(ws + 50331648);     // 48 MB  [4096][6144]
    bf16* Vtb  = (bf16*)(ws + 100663296);    // 16 MB  [B,H,D,S]
    float* cosd = (float*)(ws + 117440512);
    float* sind = (float*)(ws + 117964800);

    // fused convert: 25165824 elems -> contiguous xb|wqkv|wob
    cvt_all<<<25165824 / 1024, 256, 0, stream>>>(x, Wq, Wk, Wv, Wo, xb);

    rope_tables_k<<<(SEQ * 64) / 256, 256, 0, stream>>>(cosd, sind);

    // fused QKV projection: [4096,2048] x [6144,2048]^T -> [4096,6144]
    // 128x256 tiles: 32x24 = 768 blocks = exactly 3 rounds at 1 block/CU
    gemm128<0><<<dim3(768), 512, 0, stream>>>(
        xb, wqkv, QKV, BATCH * SEQ, QKV_LD, D_MODEL);

    const float qscale = 0.08838834764831845f;  // 1/sqrt(128)
    rope_apply<<<(BATCH * SEQ * 1024) / 256, 256, 0, stream>>>(QKV,           cosd, sind, qscale, QKV_LD);
    rope_apply<<<(BATCH * SEQ * 1024) / 256, 256, 0, stream>>>(QKV + D_MODEL, cosd, sind, 1.0f,   QKV_LD);

    transpose_v<<<dim3(SEQ / 32, HD / 32, BATCH * NH), 256, 0, stream>>>(QKV + 2 * D_MODEL, Vtb, QKV_LD);

    flash_attn<<<dim3(512), 256, 0, stream>>>(QKV, Vtb, xb /*ctx*/);

    // output projection: [4096,2048] x [2048,2048]^T -> d_out (f32)
    // 128x256 tiles: 32x8 = 256 blocks = exactly 1 round
    gemm128<1><<<dim3(256), 512, 0, stream>>>(
        xb, wob, d_out, BATCH * SEQ, D_MODEL, D_MODEL);
}